// Round 7
// baseline (14122.269 us; speedup 1.0000x reference)
//
#include <hip/hip_runtime.h>

// ---------------------------------------------------------------------------
// SAGENET: x:(8192,16384)f32 -> lin1(16384->4096,relu) -> lin2(4096->2048,relu)
// -> SAGEConv(2048->1024,relu) -> SAGEConv(1024->10,relu) -> softmax
// R7: R5's proven GEMM loop, BK 64->32 so dbuf LDS = 64 KiB -> 2 blocks/CU
//     (cross-block TLP hides the per-K-tile __syncthreads vmcnt drain, m114).
//     Zero-conflict 64B-row swizzle p = q ^ ((r>>1)&3) (R6-verified, 0 confl).
// Workspace peak: ~505.2 MiB.
// ---------------------------------------------------------------------------

typedef short  short8   __attribute__((ext_vector_type(8)));
typedef float  floatx4  __attribute__((ext_vector_type(4)));
typedef unsigned short ushort8v __attribute__((ext_vector_type(8)));
typedef unsigned short ushort4v __attribute__((ext_vector_type(4)));
typedef unsigned short ushort;

__device__ __forceinline__ ushort f2bf(float f) {
  unsigned u = __float_as_uint(f);
  u += 0x7fffu + ((u >> 16) & 1u);   // round-to-nearest-even
  return (ushort)(u >> 16);
}
__device__ __forceinline__ float bf2f(ushort h) {
  return __uint_as_float(((unsigned)h) << 16);
}

__device__ __forceinline__ void gload16(const void* g, void* l) {
  __builtin_amdgcn_global_load_lds(
      (const __attribute__((address_space(1))) void*)g,
      (__attribute__((address_space(3))) void*)l, 16, 0, 0);
}

// ---------------- f32 -> bf16 conversion (vectorized, grid-stride) ----------
__global__ __launch_bounds__(256) void cvt_f32_bf16(
    const float* __restrict__ in, ushort* __restrict__ out, long n8) {
  long i = (long)blockIdx.x * blockDim.x + threadIdx.x;
  const long stride = (long)gridDim.x * blockDim.x;
  for (; i < n8; i += stride) {
    const float4* p = (const float4*)(in + i * 8);
    float4 a = p[0], b = p[1];
    ushort8v o;
    o[0] = f2bf(a.x); o[1] = f2bf(a.y); o[2] = f2bf(a.z); o[3] = f2bf(a.w);
    o[4] = f2bf(b.x); o[5] = f2bf(b.y); o[6] = f2bf(b.z); o[7] = f2bf(b.w);
    *(ushort8v*)(out + i * 8) = o;
  }
}

// ---------------- CSR build -------------------------------------------------
__global__ void edge_count(const int* __restrict__ dst, int E, int* __restrict__ deg) {
  int e = blockIdx.x * 256 + threadIdx.x;
  if (e < E) atomicAdd(&deg[dst[e]], 1);
}

__global__ __launch_bounds__(256) void scan_k(
    const int* __restrict__ deg, int* __restrict__ offs, float* __restrict__ inv, int n) {
  __shared__ int part[256];
  const int t = threadIdx.x;
  int local[32];
  int s = 0;
  const int base = t * 32;
#pragma unroll
  for (int i = 0; i < 32; ++i) { local[i] = s; s += deg[base + i]; }
  part[t] = s;
  __syncthreads();
  for (int off = 1; off < 256; off <<= 1) {
    int v = (t >= off) ? part[t - off] : 0;
    __syncthreads();
    part[t] += v;
    __syncthreads();
  }
  const int prev = (t == 0) ? 0 : part[t - 1];
  if (t == 255) offs[n] = part[255];
#pragma unroll
  for (int i = 0; i < 32; ++i) {
    const int e = base + i;
    offs[e] = prev + local[i];
    const int d = deg[e];
    inv[e] = (d > 0) ? (1.0f / (float)d) : 0.0f;
  }
}

__global__ void edge_fill(const int* __restrict__ src, const int* __restrict__ dst, int E,
                          const int* __restrict__ offs, int* __restrict__ fill,
                          int* __restrict__ csr) {
  int e = blockIdx.x * 256 + threadIdx.x;
  if (e < E) {
    const int d = dst[e];
    const int p = offs[d] + atomicAdd(&fill[d], 1);
    csr[p] = src[e];
  }
}

// ---------------- bf16 GEMM 256x256, C = A * B^T, BK=32, 2 blocks/CU --------
// A: [M,K] bf16 row-major; B: [N,K] bf16 row-major. 8 waves (2Mx4N),
// per-wave 128x64 output (acc[8][4]). LDS 2 bufs x 32 KiB (A 16K | B 16K).
// Region = 256 rows x 64 B. Logical 16B-chunk q of row r stored at physical
// chunk q ^ ((r>>1)&3): for a 16-lane column-slice read, banks are covered
// 2-way uniform -> conflict-free ds_read_b128 (R6-measured: 0 conflicts).
// global_load_lds dest linear (chunk t); SOURCE chunk pre-permuted by the
// same involution. One __syncthreads per K-tile (drains staging).
// Block mapping: XCD x (= blockIdx%8) owns bm panels [x*nbm/8,(x+1)*nbm/8),
// bn-inner sweep; the 2 blocks sharing a CU have same bm, adjacent bn.
template <int OUT_BF16, int RELU, int HAS_BIAS>
__global__ __launch_bounds__(512, 4) void gemm256(
    const ushort* __restrict__ A, const ushort* __restrict__ Bm,
    const float* __restrict__ bias, void* __restrict__ Cout,
    int M, int N, int K) {
  extern __shared__ char smem[];   // 2 x 32768

  const int nbn = N >> 8;
  const int nbm8 = (M >> 8) >> 3;        // bm panels per XCD
  const int x = blockIdx.x & 7;          // XCD id under round-robin dispatch
  const int jj = blockIdx.x >> 3;
  const int bm = x * nbm8 + jj / nbn;
  const int bn = jj % nbn;

  const int t = threadIdx.x;
  const int w = t >> 6, lane = t & 63;
  const int wr = w >> 2, wc = w & 3;
  const int lr = lane & 15;

  // ---- staging source (pre-swizzled): thread t -> LDS chunk t = row t>>2,
  //      phys chunk t&3 -> logical q = (t&3) ^ ((t>>3)&3) ----
  const int q = (t & 3) ^ ((t >> 3) & 3);
  const ushort* Ag = A  + (size_t)(bm * 256 + (t >> 2)) * K + q * 8;
  const ushort* Bg = Bm + (size_t)(bn * 256 + (t >> 2)) * K + q * 8;
  const size_t rskip = (size_t)128 * K;
  const int ldst = w * 1024;             // wave-uniform LDS base part

  // ---- fragment read offsets ----
  const int frOff = (((lane >> 4) ^ ((lr >> 1) & 3)) << 4);
  const int rowA = (wr * 128 + lr) * 64;          // + mi*1024
  const int rowB = (wc * 64 + lr) * 64 + 16384;   // + ni*1024

  floatx4 acc[8][4] = {};
  const int NT = K >> 5;

#define STAGE(tile)                                                   \
  {                                                                   \
    const int k0_ = (tile) << 5;                                      \
    char* base_ = smem + ((tile) & 1) * 32768 + ldst;                 \
    gload16(Ag + k0_, base_);                                         \
    gload16(Ag + rskip + k0_, base_ + 8192);                          \
    gload16(Bg + k0_, base_ + 16384);                                 \
    gload16(Bg + rskip + k0_, base_ + 16384 + 8192);                  \
  }

  STAGE(0);
  __syncthreads();   // drains vmcnt: tile 0 staged

  for (int kt = 0; kt < NT; ++kt) {
    const char* pa = smem + (kt & 1) * 32768 + rowA + frOff;
    const char* pb = smem + (kt & 1) * 32768 + rowB + frOff;
    short8 af[8], bfv[4];
#pragma unroll
    for (int mi = 0; mi < 8; ++mi) af[mi] = *(const short8*)(pa + mi * 1024);
#pragma unroll
    for (int ni = 0; ni < 4; ++ni) bfv[ni] = *(const short8*)(pb + ni * 1024);

    if (kt + 1 < NT) STAGE(kt + 1);   // prefetch next tile (hidden under MFMA)

#pragma unroll
    for (int mi = 0; mi < 8; ++mi)
#pragma unroll
      for (int ni = 0; ni < 4; ++ni)
        acc[mi][ni] = __builtin_amdgcn_mfma_f32_16x16x32_bf16(af[mi], bfv[ni], acc[mi][ni], 0, 0, 0);

    __syncthreads();   // vmcnt(0)+lgkmcnt(0)+barrier: next buffer fully staged
  }

#undef STAGE

  // epilogue: C/D layout col=lane&15, row=(lane>>4)*4+j (m89-verified)
  const int row0 = bm * 256 + wr * 128 + ((lane >> 4) << 2);
  const int col0 = bn * 256 + wc * 64 + lr;
#pragma unroll
  for (int ni = 0; ni < 4; ++ni) {
    const int col = col0 + ni * 16;
    const float bv = HAS_BIAS ? bias[col] : 0.0f;
#pragma unroll
    for (int mi = 0; mi < 8; ++mi) {
#pragma unroll
      for (int j2 = 0; j2 < 4; ++j2) {
        const int row = row0 + mi * 16 + j2;
        float v = acc[mi][ni][j2] + bv;
        if (RELU) v = fmaxf(v, 0.0f);
        if (OUT_BF16)
          ((ushort*)Cout)[(size_t)row * N + col] = f2bf(v);
        else
          ((float*)Cout)[(size_t)row * N + col] = v;
      }
    }
  }
}

// ---------------- SAGE1 aggregation + combine -------------------------------
__global__ __launch_bounds__(256) void sage1_agg(
    const float* __restrict__ hlr1, const int* __restrict__ offs,
    const int* __restrict__ csr, const float* __restrict__ inv,
    const float* __restrict__ lb, ushort* __restrict__ h3) {
  const int dn = blockIdx.x;
  const int f4 = threadIdx.x * 4;
  float ax = 0.f, ay = 0.f, az = 0.f, aw = 0.f;
  const int e0 = offs[dn], e1 = offs[dn + 1];
  for (int e = e0; e < e1; ++e) {
    const int s = csr[e];
    const float4 v = *(const float4*)(hlr1 + (size_t)s * 2048 + f4);
    ax += v.x; ay += v.y; az += v.z; aw += v.w;
  }
  const float iv = inv[dn];
  const float4 hr = *(const float4*)(hlr1 + (size_t)dn * 2048 + 1024 + f4);
  const float4 bb = *(const float4*)(lb + f4);
  ushort4v o;
  o[0] = f2bf(fmaxf(ax * iv + bb.x + hr.x, 0.0f));
  o[1] = f2bf(fmaxf(ay * iv + bb.y + hr.y, 0.0f));
  o[2] = f2bf(fmaxf(az * iv + bb.z + hr.z, 0.0f));
  o[3] = f2bf(fmaxf(aw * iv + bb.w + hr.w, 0.0f));
  *(ushort4v*)(h3 + (size_t)dn * 1024 + f4) = o;
}

// ---------------- SAGE2 projections (K=1024, N=10 each) ---------------------
__global__ __launch_bounds__(64) void sage2_mm(
    const ushort* __restrict__ h3, const float* __restrict__ wl,
    const float* __restrict__ wr, float* __restrict__ hl2, float* __restrict__ hr2) {
  const int row = blockIdx.x;
  const int l = threadIdx.x;
  float hv[16];
  {
    ushort8v p0 = *(const ushort8v*)(h3 + (size_t)row * 1024 + l * 16);
    ushort8v p1 = *(const ushort8v*)(h3 + (size_t)row * 1024 + l * 16 + 8);
#pragma unroll
    for (int i = 0; i < 8; ++i) { hv[i] = bf2f(p0[i]); hv[8 + i] = bf2f(p1[i]); }
  }
  float al[10] = {}, ar[10] = {};
#pragma unroll
  for (int i = 0; i < 16; ++i) {
    const int k = l * 16 + i;
    const float h = hv[i];
#pragma unroll
    for (int j = 0; j < 10; ++j) {
      al[j] = fmaf(h, wl[j * 1024 + k], al[j]);
      ar[j] = fmaf(h, wr[j * 1024 + k], ar[j]);
    }
  }
#pragma unroll
  for (int j = 0; j < 10; ++j) {
#pragma unroll
    for (int off = 32; off > 0; off >>= 1) {
      al[j] += __shfl_down(al[j], off);
      ar[j] += __shfl_down(ar[j], off);
    }
  }
  if (l == 0) {
#pragma unroll
    for (int j = 0; j < 10; ++j) {
      hl2[(size_t)row * 10 + j] = al[j];
      hr2[(size_t)row * 10 + j] = ar[j];
    }
  }
}

// ---------------- SAGE2 aggregation + combine + softmax ---------------------
__global__ __launch_bounds__(64) void sage2_final(
    const float* __restrict__ hl2, const float* __restrict__ hr2,
    const int* __restrict__ offs, const int* __restrict__ csr,
    const float* __restrict__ inv, const float* __restrict__ lb,
    float* __restrict__ out) {
  const int dn = blockIdx.x;
  const int l = threadIdx.x;
  float a[10] = {};
  const int e0 = offs[dn], e1 = offs[dn + 1];
  for (int e = e0 + l; e < e1; e += 64) {
    const int s = csr[e];
#pragma unroll
    for (int j = 0; j < 10; ++j) a[j] += hl2[(size_t)s * 10 + j];
  }
#pragma unroll
  for (int j = 0; j < 10; ++j)
#pragma unroll
    for (int off = 32; off > 0; off >>= 1) a[j] += __shfl_down(a[j], off);
  if (l == 0) {
    const float iv = inv[dn];
    float v[10];
    float m = -1e30f;
#pragma unroll
    for (int j = 0; j < 10; ++j) {
      v[j] = fmaxf(a[j] * iv + lb[j] + hr2[(size_t)dn * 10 + j], 0.0f);
      m = fmaxf(m, v[j]);
    }
    float ssum = 0.0f;
#pragma unroll
    for (int j = 0; j < 10; ++j) { v[j] = __expf(v[j] - m); ssum += v[j]; }
    const float r = 1.0f / ssum;
#pragma unroll
    for (int j = 0; j < 10; ++j) out[(size_t)dn * 10 + j] = v[j] * r;
  }
}

// ---------------------------------------------------------------------------
extern "C" void kernel_launch(void* const* d_in, const int* in_sizes, int n_in,
                              void* d_out, int out_size, void* d_ws, size_t ws_size,
                              hipStream_t stream) {
  const float* x    = (const float*)d_in[0];
  const int*   ei   = (const int*)d_in[1];
  const float* w1   = (const float*)d_in[2];
  const float* b1   = (const float*)d_in[3];
  const float* w2   = (const float*)d_in[4];
  const float* b2   = (const float*)d_in[5];
  const float* s1lw = (const float*)d_in[6];
  const float* s1lb = (const float*)d_in[7];
  const float* s1rw = (const float*)d_in[8];
  const float* s2lw = (const float*)d_in[9];
  const float* s2lb = (const float*)d_in[10];
  const float* s2rw = (const float*)d_in[11];
  float* out = (float*)d_out;
  char* ws = (char*)d_ws;

  const int E = in_sizes[1] / 2;  // 262144
  const int Nn = 8192;

  // allow 64 KiB dynamic LDS for the GEMM instantiations (idempotent)
  hipFuncSetAttribute((const void*)&gemm256<1, 1, 1>,
                      hipFuncAttributeMaxDynamicSharedMemorySize, 65536);
  hipFuncSetAttribute((const void*)&gemm256<0, 0, 0>,
                      hipFuncAttributeMaxDynamicSharedMemorySize, 65536);

  // ---- workspace layout (bytes) ----
  ushort* xb  = (ushort*)(ws + 0L);           // 256 MiB
  ushort* w1b = (ushort*)(ws + 268435456L);   // 128 MiB
  ushort* h1  = (ushort*)(ws + 402653184L);   //  64 MiB
  ushort* w2b = (ushort*)(ws + 469762048L);   //  16 MiB
  ushort* h2  = (ushort*)(ws + 486539264L);   //  32 MiB
  ushort* ws1 = (ushort*)(ws + 520093696L);   //   8 MiB  [s1_l_w ; s1_r_w]
  char* csrb = ws + 528482304L;
  int*   deg  = (int*)(csrb);
  int*   fill = (int*)(csrb + 32768);
  int*   offs = (int*)(csrb + 65536);
  float* inv  = (float*)(csrb + 98816);
  int*   csr  = (int*)(csrb + 131584);
  // region reuse (xb dead after GEMM1, h1 dead after GEMM2):
  float*  hlr1 = (float*)(ws + 0L);                 // 64 MiB  [hl1 | hr1]
  ushort* h3   = (ushort*)(ws + 67108864L);         // 16 MiB
  float*  hl2  = (float*)(ws + 83886080L);
  float*  hr2  = (float*)(ws + 84213760L);

  const int* esrc = ei;
  const int* edst = ei + E;

  hipMemsetAsync(deg, 0, 65536, stream);  // deg + fill counters

  // bf16 conversions
  cvt_f32_bf16<<<4096, 256, 0, stream>>>(x, xb, 16777216L);
  cvt_f32_bf16<<<2048, 256, 0, stream>>>(w1, w1b, 8388608L);
  cvt_f32_bf16<<<1024, 256, 0, stream>>>(w2, w2b, 1048576L);
  cvt_f32_bf16<<<256, 256, 0, stream>>>(s1lw, ws1, 262144L);
  cvt_f32_bf16<<<256, 256, 0, stream>>>(s1rw, ws1 + 2097152L, 262144L);

  // CSR build
  edge_count<<<(E + 255) / 256, 256, 0, stream>>>(edst, E, deg);
  scan_k<<<1, 256, 0, stream>>>(deg, offs, inv, Nn);
  edge_fill<<<(E + 255) / 256, 256, 0, stream>>>(esrc, edst, E, offs, fill, csr);

  // MLP (256x256-tile GEMMs, 64 KiB dynamic LDS, 2 blocks/CU)
  gemm256<1, 1, 1><<<512, 512, 65536, stream>>>(xb, w1b, b1, h1, 8192, 4096, 16384);
  gemm256<1, 1, 1><<<256, 512, 65536, stream>>>(h1, w2b, b2, h2, 8192, 2048, 4096);
  // fused SAGE1 projections: [hl1 | hr1] = h2 @ [s1_l_w ; s1_r_w]^T
  gemm256<0, 0, 0><<<256, 512, 65536, stream>>>(h2, ws1, nullptr, hlr1, 8192, 2048, 2048);

  sage1_agg<<<8192, 256, 0, stream>>>(hlr1, offs, csr, inv, s1lb, h3);
  sage2_mm<<<8192, 64, 0, stream>>>(h3, s2lw, s2rw, hl2, hr2);
  sage2_final<<<8192, 64, 0, stream>>>(hl2, hr2, offs, csr, inv, s2lb, out);
}

// Round 8
// 1713.395 us; speedup vs baseline: 8.2423x; 8.2423x over previous
//
#include <hip/hip_runtime.h>

// ---------------------------------------------------------------------------
// SAGENET: x:(8192,16384)f32 -> lin1(16384->4096,relu) -> lin2(4096->2048,relu)
// -> SAGEConv(2048->1024,relu) -> SAGEConv(1024->10,relu) -> softmax
// R8: revert to R5's proven GEMM (256x256, BK=64, dbuf 128 KiB, zero-conflict
//     swizzle, one __syncthreads/K-tile, XCD-partitioned mapping) with ONE
//     scheduling tweak: STAGE issued at loop top (before ds_reads/MFMA, T3
//     recipe) so global loads depart earlier and the barrier drain shrinks.
//     Also: gemm3 outputs bf16 (halves store + sage1_agg gather traffic).
//     NOTE (R7 lesson): 2 blocks/CU x 8 waves needs <=128 VGPR -> impossible
//     with acc[8][4]; launch_bounds must stay (512, 2).
// Workspace peak: ~505.2 MiB.
// ---------------------------------------------------------------------------

typedef short  short8   __attribute__((ext_vector_type(8)));
typedef float  floatx4  __attribute__((ext_vector_type(4)));
typedef unsigned short ushort8v __attribute__((ext_vector_type(8)));
typedef unsigned short ushort4v __attribute__((ext_vector_type(4)));
typedef unsigned short ushort;

__device__ __forceinline__ ushort f2bf(float f) {
  unsigned u = __float_as_uint(f);
  u += 0x7fffu + ((u >> 16) & 1u);   // round-to-nearest-even
  return (ushort)(u >> 16);
}
__device__ __forceinline__ float bf2f(ushort h) {
  return __uint_as_float(((unsigned)h) << 16);
}

__device__ __forceinline__ void gload16(const void* g, void* l) {
  __builtin_amdgcn_global_load_lds(
      (const __attribute__((address_space(1))) void*)g,
      (__attribute__((address_space(3))) void*)l, 16, 0, 0);
}

// ---------------- f32 -> bf16 conversion (vectorized, grid-stride) ----------
__global__ __launch_bounds__(256) void cvt_f32_bf16(
    const float* __restrict__ in, ushort* __restrict__ out, long n8) {
  long i = (long)blockIdx.x * blockDim.x + threadIdx.x;
  const long stride = (long)gridDim.x * blockDim.x;
  for (; i < n8; i += stride) {
    const float4* p = (const float4*)(in + i * 8);
    float4 a = p[0], b = p[1];
    ushort8v o;
    o[0] = f2bf(a.x); o[1] = f2bf(a.y); o[2] = f2bf(a.z); o[3] = f2bf(a.w);
    o[4] = f2bf(b.x); o[5] = f2bf(b.y); o[6] = f2bf(b.z); o[7] = f2bf(b.w);
    *(ushort8v*)(out + i * 8) = o;
  }
}

// ---------------- CSR build -------------------------------------------------
__global__ void edge_count(const int* __restrict__ dst, int E, int* __restrict__ deg) {
  int e = blockIdx.x * 256 + threadIdx.x;
  if (e < E) atomicAdd(&deg[dst[e]], 1);
}

__global__ __launch_bounds__(256) void scan_k(
    const int* __restrict__ deg, int* __restrict__ offs, float* __restrict__ inv, int n) {
  __shared__ int part[256];
  const int t = threadIdx.x;
  int local[32];
  int s = 0;
  const int base = t * 32;
#pragma unroll
  for (int i = 0; i < 32; ++i) { local[i] = s; s += deg[base + i]; }
  part[t] = s;
  __syncthreads();
  for (int off = 1; off < 256; off <<= 1) {
    int v = (t >= off) ? part[t - off] : 0;
    __syncthreads();
    part[t] += v;
    __syncthreads();
  }
  const int prev = (t == 0) ? 0 : part[t - 1];
  if (t == 255) offs[n] = part[255];
#pragma unroll
  for (int i = 0; i < 32; ++i) {
    const int e = base + i;
    offs[e] = prev + local[i];
    const int d = deg[e];
    inv[e] = (d > 0) ? (1.0f / (float)d) : 0.0f;
  }
}

__global__ void edge_fill(const int* __restrict__ src, const int* __restrict__ dst, int E,
                          const int* __restrict__ offs, int* __restrict__ fill,
                          int* __restrict__ csr) {
  int e = blockIdx.x * 256 + threadIdx.x;
  if (e < E) {
    const int d = dst[e];
    const int p = offs[d] + atomicAdd(&fill[d], 1);
    csr[p] = src[e];
  }
}

// ---------------- bf16 GEMM 256x256, C = A * B^T ----------------------------
// A: [M,K] bf16 row-major; B: [N,K] bf16 row-major. BK=64, 8 waves (2Mx4N),
// per-wave 128x64 output (acc[8][4]), double-buffered 128 KiB LDS.
// LDS layout (per matrix tile, 256 rows x 128 B): logical (row, col16) at
// byte row*128 + ((col16 ^ (row&7))<<4)  -> conflict-free ds_read_b128
// (verified: SQ_LDS_BANK_CONFLICT == 0 in R3/R5).
// Staging: global_load_lds keeps linear LDS dest; the SOURCE global address
// is pre-permuted by the same involution. STAGE issued at loop TOP (T3).
// Block mapping: XCD x (= blockIdx%8, round-robin dispatch) owns bm panels
// [x*nbm/8, (x+1)*nbm/8), bn-inner sweep.
template <int OUT_BF16, int RELU, int HAS_BIAS>
__global__ __launch_bounds__(512, 2) void gemm256(
    const ushort* __restrict__ A, const ushort* __restrict__ Bm,
    const float* __restrict__ bias, void* __restrict__ Cout,
    int M, int N, int K) {
  extern __shared__ char smem[];   // 131072 B: buf0{A,B}, buf1{A,B} each 32 KiB

  const int nbn = N >> 8;
  const int nbm8 = (M >> 8) >> 3;        // bm panels per XCD (M=8192 -> 4)
  const int x = blockIdx.x & 7;          // XCD id under round-robin dispatch
  const int j = blockIdx.x >> 3;         // sequence within this XCD
  const int bm = x * nbm8 + j / nbn;
  const int bn = j % nbn;

  const int t = threadIdx.x;
  const int w = t >> 6, lane = t & 63;
  const int wr = w >> 2, wc = w & 3;

  // ---- staging addresses (source pre-swizzled) ----
  const int cswz = (t & 7) ^ ((t >> 3) & 7);
  const ushort* Ag = A  + (size_t)(bm * 256 + (t >> 3)) * K + cswz * 8;
  const ushort* Bg = Bm + (size_t)(bn * 256 + (t >> 3)) * K + cswz * 8;
  const int stOff = w * 1024;

  // ---- fragment read addresses (swizzled) ----
  const int rA = wr * 128 + (lane & 15);
  const int rB = wc * 64 + (lane & 15);
  const int s0 = (((lane >> 4) ^ (lane & 7)) << 4);  // kh=0 slot byte offset
  // kh=1 slot = s0 ^ 64

  floatx4 acc[8][4] = {};

  const int NT = K >> 6;

  // prologue: stage K-tile 0 into buffer 0
  {
    char* la = smem + stOff;
    char* lb = la + 32768;
#pragma unroll
    for (int i = 0; i < 4; ++i) gload16(Ag + (size_t)(i * 64) * K, la + i * 8192);
#pragma unroll
    for (int i = 0; i < 4; ++i) gload16(Bg + (size_t)(i * 64) * K, lb + i * 8192);
  }
  __syncthreads();

  for (int kt = 0; kt < NT; ++kt) {
    // STAGE first (T3): get next tile's global loads in flight before the
    // ds_read+MFMA phase, shrinking the vmcnt drain at the end barrier.
    if (kt + 1 < NT) {
      const int k0 = (kt + 1) << 6;
      char* la = smem + ((kt + 1) & 1) * 65536 + stOff;
      char* lb = la + 32768;
#pragma unroll
      for (int i = 0; i < 4; ++i) gload16(Ag + (size_t)(i * 64) * K + k0, la + i * 8192);
#pragma unroll
      for (int i = 0; i < 4; ++i) gload16(Bg + (size_t)(i * 64) * K + k0, lb + i * 8192);
    }

    const char* pa = smem + (kt & 1) * 65536 + rA * 128;
    const char* pb = smem + (kt & 1) * 65536 + 32768 + rB * 128;

    // kh=0 fragments
    short8 a0[8], b0[4];
#pragma unroll
    for (int mi = 0; mi < 8; ++mi) a0[mi] = *(const short8*)(pa + mi * 2048 + s0);
#pragma unroll
    for (int ni = 0; ni < 4; ++ni) b0[ni] = *(const short8*)(pb + ni * 2048 + s0);

#pragma unroll
    for (int mi = 0; mi < 8; ++mi)
#pragma unroll
      for (int ni = 0; ni < 4; ++ni)
        acc[mi][ni] = __builtin_amdgcn_mfma_f32_16x16x32_bf16(a0[mi], b0[ni], acc[mi][ni], 0, 0, 0);

    // kh=1 fragments
    short8 a1[8], b1[4];
#pragma unroll
    for (int mi = 0; mi < 8; ++mi) a1[mi] = *(const short8*)(pa + mi * 2048 + (s0 ^ 64));
#pragma unroll
    for (int ni = 0; ni < 4; ++ni) b1[ni] = *(const short8*)(pb + ni * 2048 + (s0 ^ 64));

#pragma unroll
    for (int mi = 0; mi < 8; ++mi)
#pragma unroll
      for (int ni = 0; ni < 4; ++ni)
        acc[mi][ni] = __builtin_amdgcn_mfma_f32_16x16x32_bf16(a1[mi], b1[ni], acc[mi][ni], 0, 0, 0);

    __syncthreads();  // vmcnt(0)+lgkmcnt(0)+barrier: next buffer fully staged
  }

  // epilogue: C/D layout col=lane&15, row=(lane>>4)*4+j (m89-verified)
  const int row0 = bm * 256 + wr * 128 + ((lane >> 4) << 2);
  const int col0 = bn * 256 + wc * 64 + (lane & 15);
#pragma unroll
  for (int ni = 0; ni < 4; ++ni) {
    const int col = col0 + ni * 16;
    const float bv = HAS_BIAS ? bias[col] : 0.0f;
#pragma unroll
    for (int mi = 0; mi < 8; ++mi) {
#pragma unroll
      for (int j2 = 0; j2 < 4; ++j2) {
        const int row = row0 + mi * 16 + j2;
        float v = acc[mi][ni][j2] + bv;
        if (RELU) v = fmaxf(v, 0.0f);
        if (OUT_BF16)
          ((ushort*)Cout)[(size_t)row * N + col] = f2bf(v);
        else
          ((float*)Cout)[(size_t)row * N + col] = v;
      }
    }
  }
}

// ---------------- SAGE1 aggregation + combine (bf16 hlr1) -------------------
// h3[dst] = relu( inv_deg[dst]*sum_{src} hlr1[src][0:1024] + s1_l_b
//                 + hlr1[dst][1024:2048] )   (bf16 in, f32 accum, bf16 out)
__global__ __launch_bounds__(256) void sage1_agg(
    const ushort* __restrict__ hlr1, const int* __restrict__ offs,
    const int* __restrict__ csr, const float* __restrict__ inv,
    const float* __restrict__ lb, ushort* __restrict__ h3) {
  const int dn = blockIdx.x;
  const int f4 = threadIdx.x * 4;
  float ax = 0.f, ay = 0.f, az = 0.f, aw = 0.f;
  const int e0 = offs[dn], e1 = offs[dn + 1];
  for (int e = e0; e < e1; ++e) {
    const int s = csr[e];
    const ushort4v v = *(const ushort4v*)(hlr1 + (size_t)s * 2048 + f4);
    ax += bf2f(v[0]); ay += bf2f(v[1]); az += bf2f(v[2]); aw += bf2f(v[3]);
  }
  const float iv = inv[dn];
  const ushort4v hr = *(const ushort4v*)(hlr1 + (size_t)dn * 2048 + 1024 + f4);
  const float4 bb = *(const float4*)(lb + f4);
  ushort4v o;
  o[0] = f2bf(fmaxf(ax * iv + bb.x + bf2f(hr[0]), 0.0f));
  o[1] = f2bf(fmaxf(ay * iv + bb.y + bf2f(hr[1]), 0.0f));
  o[2] = f2bf(fmaxf(az * iv + bb.z + bf2f(hr[2]), 0.0f));
  o[3] = f2bf(fmaxf(aw * iv + bb.w + bf2f(hr[3]), 0.0f));
  *(ushort4v*)(h3 + (size_t)dn * 1024 + f4) = o;
}

// ---------------- SAGE2 projections (K=1024, N=10 each) ---------------------
__global__ __launch_bounds__(64) void sage2_mm(
    const ushort* __restrict__ h3, const float* __restrict__ wl,
    const float* __restrict__ wr, float* __restrict__ hl2, float* __restrict__ hr2) {
  const int row = blockIdx.x;
  const int l = threadIdx.x;
  float hv[16];
  {
    ushort8v p0 = *(const ushort8v*)(h3 + (size_t)row * 1024 + l * 16);
    ushort8v p1 = *(const ushort8v*)(h3 + (size_t)row * 1024 + l * 16 + 8);
#pragma unroll
    for (int i = 0; i < 8; ++i) { hv[i] = bf2f(p0[i]); hv[8 + i] = bf2f(p1[i]); }
  }
  float al[10] = {}, ar[10] = {};
#pragma unroll
  for (int i = 0; i < 16; ++i) {
    const int k = l * 16 + i;
    const float h = hv[i];
#pragma unroll
    for (int j = 0; j < 10; ++j) {
      al[j] = fmaf(h, wl[j * 1024 + k], al[j]);
      ar[j] = fmaf(h, wr[j * 1024 + k], ar[j]);
    }
  }
#pragma unroll
  for (int j = 0; j < 10; ++j) {
#pragma unroll
    for (int off = 32; off > 0; off >>= 1) {
      al[j] += __shfl_down(al[j], off);
      ar[j] += __shfl_down(ar[j], off);
    }
  }
  if (l == 0) {
#pragma unroll
    for (int j = 0; j < 10; ++j) {
      hl2[(size_t)row * 10 + j] = al[j];
      hr2[(size_t)row * 10 + j] = ar[j];
    }
  }
}

// ---------------- SAGE2 aggregation + combine + softmax ---------------------
__global__ __launch_bounds__(64) void sage2_final(
    const float* __restrict__ hl2, const float* __restrict__ hr2,
    const int* __restrict__ offs, const int* __restrict__ csr,
    const float* __restrict__ inv, const float* __restrict__ lb,
    float* __restrict__ out) {
  const int dn = blockIdx.x;
  const int l = threadIdx.x;
  float a[10] = {};
  const int e0 = offs[dn], e1 = offs[dn + 1];
  for (int e = e0 + l; e < e1; e += 64) {
    const int s = csr[e];
#pragma unroll
    for (int j = 0; j < 10; ++j) a[j] += hl2[(size_t)s * 10 + j];
  }
#pragma unroll
  for (int j = 0; j < 10; ++j)
#pragma unroll
    for (int off = 32; off > 0; off >>= 1) a[j] += __shfl_down(a[j], off);
  if (l == 0) {
    const float iv = inv[dn];
    float v[10];
    float m = -1e30f;
#pragma unroll
    for (int j = 0; j < 10; ++j) {
      v[j] = fmaxf(a[j] * iv + lb[j] + hr2[(size_t)dn * 10 + j], 0.0f);
      m = fmaxf(m, v[j]);
    }
    float ssum = 0.0f;
#pragma unroll
    for (int j = 0; j < 10; ++j) { v[j] = __expf(v[j] - m); ssum += v[j]; }
    const float r = 1.0f / ssum;
#pragma unroll
    for (int j = 0; j < 10; ++j) out[(size_t)dn * 10 + j] = v[j] * r;
  }
}

// ---------------------------------------------------------------------------
extern "C" void kernel_launch(void* const* d_in, const int* in_sizes, int n_in,
                              void* d_out, int out_size, void* d_ws, size_t ws_size,
                              hipStream_t stream) {
  const float* x    = (const float*)d_in[0];
  const int*   ei   = (const int*)d_in[1];
  const float* w1   = (const float*)d_in[2];
  const float* b1   = (const float*)d_in[3];
  const float* w2   = (const float*)d_in[4];
  const float* b2   = (const float*)d_in[5];
  const float* s1lw = (const float*)d_in[6];
  const float* s1lb = (const float*)d_in[7];
  const float* s1rw = (const float*)d_in[8];
  const float* s2lw = (const float*)d_in[9];
  const float* s2lb = (const float*)d_in[10];
  const float* s2rw = (const float*)d_in[11];
  float* out = (float*)d_out;
  char* ws = (char*)d_ws;

  const int E = in_sizes[1] / 2;  // 262144
  const int Nn = 8192;

  // allow 128 KiB dynamic LDS for the GEMM instantiations (idempotent)
  hipFuncSetAttribute((const void*)&gemm256<1, 1, 1>,
                      hipFuncAttributeMaxDynamicSharedMemorySize, 131072);
  hipFuncSetAttribute((const void*)&gemm256<1, 0, 0>,
                      hipFuncAttributeMaxDynamicSharedMemorySize, 131072);

  // ---- workspace layout (bytes) ----
  ushort* xb  = (ushort*)(ws + 0L);           // 256 MiB
  ushort* w1b = (ushort*)(ws + 268435456L);   // 128 MiB
  ushort* h1  = (ushort*)(ws + 402653184L);   //  64 MiB
  ushort* w2b = (ushort*)(ws + 469762048L);   //  16 MiB
  ushort* h2  = (ushort*)(ws + 486539264L);   //  32 MiB
  ushort* ws1 = (ushort*)(ws + 520093696L);   //   8 MiB  [s1_l_w ; s1_r_w]
  char* csrb = ws + 528482304L;
  int*   deg  = (int*)(csrb);
  int*   fill = (int*)(csrb + 32768);
  int*   offs = (int*)(csrb + 65536);
  float* inv  = (float*)(csrb + 98816);
  int*   csr  = (int*)(csrb + 131584);
  // region reuse (xb dead after GEMM1, h1 dead after GEMM2):
  ushort* hlr1 = (ushort*)(ws + 0L);                // 32 MiB bf16 [hl1 | hr1]
  ushort* h3   = (ushort*)(ws + 67108864L);         // 16 MiB
  float*  hl2  = (float*)(ws + 83886080L);
  float*  hr2  = (float*)(ws + 84213760L);

  const int* esrc = ei;
  const int* edst = ei + E;

  hipMemsetAsync(deg, 0, 65536, stream);  // deg + fill counters

  // bf16 conversions
  cvt_f32_bf16<<<4096, 256, 0, stream>>>(x, xb, 16777216L);
  cvt_f32_bf16<<<2048, 256, 0, stream>>>(w1, w1b, 8388608L);
  cvt_f32_bf16<<<1024, 256, 0, stream>>>(w2, w2b, 1048576L);
  cvt_f32_bf16<<<256, 256, 0, stream>>>(s1lw, ws1, 262144L);
  cvt_f32_bf16<<<256, 256, 0, stream>>>(s1rw, ws1 + 2097152L, 262144L);

  // CSR build
  edge_count<<<(E + 255) / 256, 256, 0, stream>>>(edst, E, deg);
  scan_k<<<1, 256, 0, stream>>>(deg, offs, inv, Nn);
  edge_fill<<<(E + 255) / 256, 256, 0, stream>>>(esrc, edst, E, offs, fill, csr);

  // MLP (256x256-tile GEMMs, 128 KiB dynamic LDS)
  gemm256<1, 1, 1><<<512, 512, 131072, stream>>>(xb, w1b, b1, h1, 8192, 4096, 16384);
  gemm256<1, 1, 1><<<256, 512, 131072, stream>>>(h1, w2b, b2, h2, 8192, 2048, 4096);
  // fused SAGE1 projections: [hl1 | hr1] = h2 @ [s1_l_w ; s1_r_w]^T  (bf16 out)
  gemm256<1, 0, 0><<<256, 512, 131072, stream>>>(h2, ws1, nullptr, hlr1, 8192, 2048, 2048);

  sage1_agg<<<8192, 256, 0, stream>>>(hlr1, offs, csr, inv, s1lb, h3);
  sage2_mm<<<8192, 64, 0, stream>>>(h3, s2lw, s2rw, hl2, hr2);
  sage2_final<<<8192, 64, 0, stream>>>(hl2, hr2, offs, csr, inv, s2lb, out);
}